// Round 15
// baseline (218.350 us; speedup 1.0000x reference)
//
#include <hip/hip_runtime.h>

// RNN: h_{t+1} = relu(x_t*W_ih^T + b_ih + b_hh + W_hh·h_t), out = fc(h_T).
// B=4096, T=1000, H=20.
//
// R15: BATCH-PAIR PACKING. Each v2f holds (batch 2p, batch 2p+1). 16 lanes
// per pair, 2048 pairs = 512 waves (2 SIMDs/CU busy). Packing is natural
// everywhere: h pairs exit step t exactly in the multiplier format step t+1
// needs (no splats); weights splatted {w,w} ONCE outside the loop; folds act
// per 32-bit half (per-batch lane reduction, 10 DPP-adds per batch-step,
// same as before); relu = pk_max in place. Per step-pair ~57 insts =
// ~28.5 per batch-step vs ~45 measured in R14.
//
// Alternating-role scheme per lane (a,bq) unchanged:
//   EVEN step: rows a-group x k-slice bq; reduce over bq = quad_perm folds.
//   ODD  step: rows bq-group x k-slice a; reduce over a = row_ror:4/8 folds.
// R13's 20-step double-buffered x prefetch kept (per batch of the pair).

#define TT 1000

typedef float v2f __attribute__((ext_vector_type(2)));

struct C5 { v2f c0, c1, c2, c3, c4; };   // 5 packed (batch-pair) values

#define SPL(s) ((v2f){(s), (s)})

#define PIN(v)  asm volatile("" : "+v"(v))
__device__ __forceinline__ void pinc(C5& c) {
    PIN(c.c0); PIN(c.c1); PIN(c.c2); PIN(c.c3); PIN(c.c4);
}
__device__ __forceinline__ void keepc(const C5& c) {
    asm volatile("" :: "v"(c.c0), "v"(c.c1), "v"(c.c2), "v"(c.c3), "v"(c.c4));
}

template <int CTRL>
__device__ __forceinline__ float dpp_f(float v) {
    // old=0 + bound_ctrl + full masks -> GCNDPPCombine can fuse into v_add_f32_dpp
    return __int_as_float(__builtin_amdgcn_update_dpp(
        0, __float_as_int(v), CTRL, 0xF, 0xF, true));
}

#define QP_XOR1 0xB1   // quad_perm [1,0,3,2]
#define QP_XOR2 0x4E   // quad_perm [2,3,0,1]
#define ROR4   0x124   // row_ror:4  (within 16-lane row)
#define ROR8   0x128   // row_ror:8

// fold both halves of a pair across lanes (each half = one batch)
template <int C>
__device__ __forceinline__ v2f fold_pair(v2f a) {
    float lo = a.x, hi = a.y;
    float tl = dpp_f<C>(lo), th = dpp_f<C>(hi);
    lo += tl; hi += th;
    return (v2f){lo, hi};
}

// One timestep for the batch pair. Tile columns w0..w4 (w{k}.c{j} =
// splat of W[row j][col k]); h.ck = pair of h[k-slice element k].
template <int C1, int C2>
__device__ __forceinline__ void step(v2f xp, C5& h,
                                     const C5& w0, const C5& w1, const C5& w2,
                                     const C5& w3, const C5& w4,
                                     const C5& wih, const C5& bias) {
    v2f a0 = __builtin_elementwise_fma(xp, wih.c0, bias.c0);
    v2f a1 = __builtin_elementwise_fma(xp, wih.c1, bias.c1);
    v2f a2 = __builtin_elementwise_fma(xp, wih.c2, bias.c2);
    v2f a3 = __builtin_elementwise_fma(xp, wih.c3, bias.c3);
    v2f a4 = __builtin_elementwise_fma(xp, wih.c4, bias.c4);

#define KCOL(hp, wc)                                          \
    a0 = __builtin_elementwise_fma(hp, (wc).c0, a0);          \
    a1 = __builtin_elementwise_fma(hp, (wc).c1, a1);          \
    a2 = __builtin_elementwise_fma(hp, (wc).c2, a2);          \
    a3 = __builtin_elementwise_fma(hp, (wc).c3, a3);          \
    a4 = __builtin_elementwise_fma(hp, (wc).c4, a4);
    KCOL(h.c0, w0) KCOL(h.c1, w1) KCOL(h.c2, w2) KCOL(h.c3, w3) KCOL(h.c4, w4)
#undef KCOL

    a0 = fold_pair<C1>(a0); a1 = fold_pair<C1>(a1); a2 = fold_pair<C1>(a2);
    a3 = fold_pair<C1>(a3); a4 = fold_pair<C1>(a4);
    a0 = fold_pair<C2>(a0); a1 = fold_pair<C2>(a1); a2 = fold_pair<C2>(a2);
    a3 = fold_pair<C2>(a3); a4 = fold_pair<C2>(a4);

    const v2f z = {0.f, 0.f};
    h.c0 = __builtin_elementwise_max(a0, z);
    h.c1 = __builtin_elementwise_max(a1, z);
    h.c2 = __builtin_elementwise_max(a2, z);
    h.c3 = __builtin_elementwise_max(a3, z);
    h.c4 = __builtin_elementwise_max(a4, z);
}

__global__ void
__attribute__((amdgpu_flat_work_group_size(64, 64), amdgpu_waves_per_eu(1, 1)))
rnn_bp_kernel(const float* __restrict__ x,
              const float* __restrict__ W_ih,
              const float* __restrict__ W_hh,
              const float* __restrict__ b_ih,
              const float* __restrict__ b_hh,
              const float* __restrict__ fc_w,
              const float* __restrict__ fc_b,
              float* __restrict__ out) {
    const int tid = blockIdx.x * 64 + threadIdx.x;
    const int p   = tid >> 4;     // batch pair index, 0..2047
    const int gl  = tid & 15;     // lane in 16-lane group
    const int a   = gl >> 2;      // quad index
    const int bq  = gl & 3;       // position in quad

    // --- weight tiles, column-major, SPLATTED once (both halves = same w)
    C5 we0, we1, we2, we3, we4;   // even: rows a-group, cols bq-group
    C5 wo0, wo1, wo2, wo3, wo4;   // odd:  rows bq-group, cols a-group
#define LOADC(wk, k, rbase, cbase)                                            \
    { (wk).c0 = SPL(W_hh[((rbase) + 0) * 20 + (cbase) + (k)]);                \
      (wk).c1 = SPL(W_hh[((rbase) + 1) * 20 + (cbase) + (k)]);                \
      (wk).c2 = SPL(W_hh[((rbase) + 2) * 20 + (cbase) + (k)]);                \
      (wk).c3 = SPL(W_hh[((rbase) + 3) * 20 + (cbase) + (k)]);                \
      (wk).c4 = SPL(W_hh[((rbase) + 4) * 20 + (cbase) + (k)]); }
    LOADC(we0, 0, a * 5, bq * 5) LOADC(we1, 1, a * 5, bq * 5)
    LOADC(we2, 2, a * 5, bq * 5) LOADC(we3, 3, a * 5, bq * 5)
    LOADC(we4, 4, a * 5, bq * 5)
    LOADC(wo0, 0, bq * 5, a * 5) LOADC(wo1, 1, bq * 5, a * 5)
    LOADC(wo2, 2, bq * 5, a * 5) LOADC(wo3, 3, bq * 5, a * 5)
    LOADC(wo4, 4, bq * 5, a * 5)
#undef LOADC

    const bool eact = (bq == 0);  // even steps: reduction over bq
    const bool oact = (a == 0);   // odd steps:  reduction over a
    C5 wie, bie, wio, bio;
#define LOADIB(wv, bv, base, act)                                             \
    { const float* pw = W_ih + (base);                                        \
      const float* p1 = b_ih + (base);                                        \
      const float* p2 = b_hh + (base);                                        \
      (wv).c0 = SPL((act) ? pw[0] : 0.f);                                     \
      (wv).c1 = SPL((act) ? pw[1] : 0.f);                                     \
      (wv).c2 = SPL((act) ? pw[2] : 0.f);                                     \
      (wv).c3 = SPL((act) ? pw[3] : 0.f);                                     \
      (wv).c4 = SPL((act) ? pw[4] : 0.f);                                     \
      (bv).c0 = SPL((act) ? (p1[0] + p2[0]) : 0.f);                           \
      (bv).c1 = SPL((act) ? (p1[1] + p2[1]) : 0.f);                           \
      (bv).c2 = SPL((act) ? (p1[2] + p2[2]) : 0.f);                           \
      (bv).c3 = SPL((act) ? (p1[3] + p2[3]) : 0.f);                           \
      (bv).c4 = SPL((act) ? (p1[4] + p2[4]) : 0.f); }
    LOADIB(wie, bie, a * 5,  eact)
    LOADIB(wio, bio, bq * 5, oact)
#undef LOADIB

    pinc(we0); pinc(we1); pinc(we2); pinc(we3); pinc(we4);
    pinc(wo0); pinc(wo1); pinc(wo2); pinc(wo3); pinc(wo4);
    pinc(wie); pinc(bie); pinc(wio); pinc(bio);

    C5 h;
    h.c0 = SPL(0.f); h.c1 = SPL(0.f); h.c2 = SPL(0.f);
    h.c3 = SPL(0.f); h.c4 = SPL(0.f);

    const float* __restrict__ xb0 = x + (size_t)(2 * p) * TT;       // batch 2p
    const float* __restrict__ xb1 = xb0 + TT;                        // batch 2p+1

    // --- 20-step blocks, double-buffered, one buffer set per batch half.
#define LOAD5(P0, P1, P2, P3, P4, src, off)             \
    P0 = *(const float4*)((src) + (off));               \
    P1 = *(const float4*)((src) + (off) + 4);           \
    P2 = *(const float4*)((src) + (off) + 8);           \
    P3 = *(const float4*)((src) + (off) + 12);          \
    P4 = *(const float4*)((src) + (off) + 16);

#define STEP_E(xp) step<QP_XOR1, QP_XOR2>(xp, h, we0, we1, we2, we3, we4, wie, bie);
#define STEP_O(xp) step<ROR4,    ROR8   >(xp, h, wo0, wo1, wo2, wo3, wo4, wio, bio);
    // Qa = batch-2p float4, Qc = batch-2p+1 float4; pack per substep
#define RUN4(Qa, Qc)                              \
    STEP_E(((v2f){Qa.x, Qc.x}))                   \
    STEP_O(((v2f){Qa.y, Qc.y}))                   \
    STEP_E(((v2f){Qa.z, Qc.z}))                   \
    STEP_O(((v2f){Qa.w, Qc.w}))
#define RUN20(PA0, PA1, PA2, PA3, PA4, PC0, PC1, PC2, PC3, PC4)  \
    RUN4(PA0, PC0) RUN4(PA1, PC1) RUN4(PA2, PC2) RUN4(PA3, PC3) RUN4(PA4, PC4)

    float4 A0, A1, A2, A3, A4, B0, B1, B2, B3, B4;   // batch 2p
    float4 Ca0, Ca1, Ca2, Ca3, Ca4, D0, D1, D2, D3, D4; // batch 2p+1
    LOAD5(A0, A1, A2, A3, A4, xb0, 0)     // steps 0..19
    LOAD5(Ca0, Ca1, Ca2, Ca3, Ca4, xb1, 0)
    LOAD5(B0, B1, B2, B3, B4, xb0, 20)    // steps 20..39
    LOAD5(D0, D1, D2, D3, D4, xb1, 20)

    for (int it = 0; it < 25; ++it) {
        const int base = it * 40;
        const int na = (it < 24) ? base + 40 : 920;  // clamped; stale unused
        const int nb = (it < 24) ? base + 60 : 940;

        RUN20(A0, A1, A2, A3, A4, Ca0, Ca1, Ca2, Ca3, Ca4)   // base..base+19
        LOAD5(A0, A1, A2, A3, A4, xb0, na)
        LOAD5(Ca0, Ca1, Ca2, Ca3, Ca4, xb1, na)
        RUN20(B0, B1, B2, B3, B4, D0, D1, D2, D3, D4)        // base+20..base+39
        LOAD5(B0, B1, B2, B3, B4, xb0, nb)
        LOAD5(D0, D1, D2, D3, D4, xb1, nb)
    }

#undef RUN20
#undef RUN4
#undef STEP_E
#undef STEP_O
#undef LOAD5

    keepc(we0); keepc(we1); keepc(we2); keepc(we3); keepc(we4);
    keepc(wo0); keepc(wo1); keepc(wo2); keepc(wo3); keepc(wo4);
    keepc(wie); keepc(bie); keepc(wio); keepc(bio);

    // After step 999 (odd role), lane (a,bq) holds h[bq-slice] pairs
    // replicated over a. Mask fc weights to a==0 lanes, packed dot, then
    // per-half shfl reduction across the 16-lane group.
    v2f dotp = {0.f, 0.f};
    {
        const float* pf = fc_w + bq * 5;
        dotp = __builtin_elementwise_fma(h.c0, SPL(oact ? pf[0] : 0.f), dotp);
        dotp = __builtin_elementwise_fma(h.c1, SPL(oact ? pf[1] : 0.f), dotp);
        dotp = __builtin_elementwise_fma(h.c2, SPL(oact ? pf[2] : 0.f), dotp);
        dotp = __builtin_elementwise_fma(h.c3, SPL(oact ? pf[3] : 0.f), dotp);
        dotp = __builtin_elementwise_fma(h.c4, SPL(oact ? pf[4] : 0.f), dotp);
    }
    float d0 = dotp.x, d1 = dotp.y;
    d0 += __shfl_xor(d0, 1, 16); d1 += __shfl_xor(d1, 1, 16);
    d0 += __shfl_xor(d0, 2, 16); d1 += __shfl_xor(d1, 2, 16);
    d0 += __shfl_xor(d0, 4, 16); d1 += __shfl_xor(d1, 4, 16);
    d0 += __shfl_xor(d0, 8, 16); d1 += __shfl_xor(d1, 8, 16);

    if (gl == 0) {
        const float fb = fc_b[0];
        out[2 * p]     = d0 + fb;
        out[2 * p + 1] = d1 + fb;
    }
}

extern "C" void kernel_launch(void* const* d_in, const int* in_sizes, int n_in,
                              void* d_out, int out_size, void* d_ws, size_t ws_size,
                              hipStream_t stream) {
    const float* x    = (const float*)d_in[0];
    const float* W_ih = (const float*)d_in[1];
    const float* W_hh = (const float*)d_in[2];
    const float* b_ih = (const float*)d_in[3];
    const float* b_hh = (const float*)d_in[4];
    const float* fc_w = (const float*)d_in[5];
    const float* fc_b = (const float*)d_in[6];
    float* out = (float*)d_out;

    // 2048 batch pairs * 16 lanes = 32768 threads; 64-thread blocks -> 512
    // single-wave blocks (2 per CU).
    const int block = 64;
    const int grid  = (2048 * 16) / block;  // 512 blocks
    rnn_bp_kernel<<<grid, block, 0, stream>>>(x, W_ih, W_hh, b_ih, b_hh,
                                              fc_w, fc_b, out);
}

// Round 16
// 145.468 us; speedup vs baseline: 1.5010x; 1.5010x over previous
//
#include <hip/hip_runtime.h>

// RNN: h_{t+1} = relu(x_t*W_ih^T + b_ih + b_hh + W_hh·h_t), out = fc(h_T).
// B=4096, T=1000, H=20.  16 lanes per batch, 1024 waves = 1 per SIMD.
//
// Alternating-role scheme: lane (a,bq):
//   EVEN step: rows a-group x k-slice bq; reduce over bq = quad_perm folds.
//   ODD  step: rows bq-group x k-slice a; reduce over a = row_ror:4/8 folds.
// R14 (91.5 us, best): rows packed (r0,r1),(r2,r3),r4 as v2f -> pk_fma.
// R15 (batch-pair packing): 165 us — fold pack/unpack scalarized it. Reverted.
//
// R16: all splats as SWIZZLES of live pairs (h01.xx, h01.yy, xp.xx, ...) so
// the backend can encode them as VOP3P op_sel (free) instead of v_mov pairs.
// ~8 movs/step (~20% of issue) are at stake. Everything else == R14.

#define TT 1000

typedef float v2f __attribute__((ext_vector_type(2)));

// one column k of a 5x5 tile: rows 0..4 packed as (r0,r1),(r2,r3),r4
struct Col { v2f p01, p23; float v4; };

#define PIN(v)  asm volatile("" : "+v"(v))
__device__ __forceinline__ void pinc(Col& c) {
    PIN(c.p01); PIN(c.p23); PIN(c.v4);
}
__device__ __forceinline__ void keepc(const Col& c) {
    asm volatile("" :: "v"(c.p01), "v"(c.p23), "v"(c.v4));
}

template <int CTRL>
__device__ __forceinline__ float dpp_f(float v) {
    // old=0 + bound_ctrl + full masks -> GCNDPPCombine fuses into v_add_f32_dpp
    return __int_as_float(__builtin_amdgcn_update_dpp(
        0, __float_as_int(v), CTRL, 0xF, 0xF, true));
}

#define QP_XOR1 0xB1   // quad_perm [1,0,3,2]
#define QP_XOR2 0x4E   // quad_perm [2,3,0,1]
#define ROR4   0x124   // row_ror:4  (within 16-lane row)
#define ROR8   0x128   // row_ror:8

// One timestep. xp = v2f holding 2 consecutive x's; HALF picks which one.
// h = (h01,h23,h4); columns wc0..wc4 packed by rows.
template <int HALF, int C1, int C2>
__device__ __forceinline__ void step(v2f xp, v2f& h01, v2f& h23, float& h4,
                                     const Col& wc0, const Col& wc1,
                                     const Col& wc2, const Col& wc3,
                                     const Col& wc4,
                                     const Col& wih, const Col& bias) {
    const v2f xs = (HALF == 0) ? xp.xx : xp.yy;     // op_sel-able splat
    const float xt = (HALF == 0) ? xp.x : xp.y;

    v2f  A01 = __builtin_elementwise_fma(xs, wih.p01, bias.p01);
    v2f  A23 = __builtin_elementwise_fma(xs, wih.p23, bias.p23);
    float a4 = __builtin_fmaf(xt, wih.v4, bias.v4);

#define KCOL(hs, hk, wc)                                           \
    A01 = __builtin_elementwise_fma(hs, (wc).p01, A01);            \
    A23 = __builtin_elementwise_fma(hs, (wc).p23, A23);            \
    a4  = __builtin_fmaf(hk, (wc).v4, a4);
    KCOL(h01.xx, h01.x, wc0)
    KCOL(h01.yy, h01.y, wc1)
    KCOL(h23.xx, h23.x, wc2)
    KCOL(h23.yy, h23.y, wc3)
    { const v2f h4s = {h4, h4};
      KCOL(h4s, h4, wc4) }
#undef KCOL

    // folds on the five 32-bit halves (breadth-first: movs then adds)
    float b0 = A01.x, b1 = A01.y, b2 = A23.x, b3 = A23.y, b4 = a4;
    {
        float t0 = dpp_f<C1>(b0), t1 = dpp_f<C1>(b1), t2 = dpp_f<C1>(b2),
              t3 = dpp_f<C1>(b3), t4 = dpp_f<C1>(b4);
        b0 += t0; b1 += t1; b2 += t2; b3 += t3; b4 += t4;
    }
    {
        float t0 = dpp_f<C2>(b0), t1 = dpp_f<C2>(b1), t2 = dpp_f<C2>(b2),
              t3 = dpp_f<C2>(b3), t4 = dpp_f<C2>(b4);
        b0 += t0; b1 += t1; b2 += t2; b3 += t3; b4 += t4;
    }

    const v2f z = {0.f, 0.f};
    v2f r01 = {b0, b1};
    v2f r23 = {b2, b3};
    h01 = __builtin_elementwise_max(r01, z);   // v_pk_max_f32
    h23 = __builtin_elementwise_max(r23, z);
    h4  = fmaxf(b4, 0.f);
}

__global__ void
__attribute__((amdgpu_flat_work_group_size(64, 64), amdgpu_waves_per_eu(1, 1)))
rnn_os_kernel(const float* __restrict__ x,
              const float* __restrict__ W_ih,
              const float* __restrict__ W_hh,
              const float* __restrict__ b_ih,
              const float* __restrict__ b_hh,
              const float* __restrict__ fc_w,
              const float* __restrict__ fc_b,
              float* __restrict__ out) {
    const int tid = blockIdx.x * 64 + threadIdx.x;
    const int b   = tid >> 4;     // batch element
    const int gl  = tid & 15;     // lane in 16-lane group
    const int a   = gl >> 2;      // quad index
    const int bq  = gl & 3;       // position in quad

    // --- weight tiles, column-major, packed rows
    Col we0, we1, we2, we3, we4;  // even: rows a-group, cols bq-group
    Col wo0, wo1, wo2, wo3, wo4;  // odd:  rows bq-group, cols a-group
#define LOADC(wk, k, rbase, cbase)                                            \
    { (wk).p01 = (v2f){ W_hh[((rbase) + 0) * 20 + (cbase) + (k)],             \
                        W_hh[((rbase) + 1) * 20 + (cbase) + (k)] };           \
      (wk).p23 = (v2f){ W_hh[((rbase) + 2) * 20 + (cbase) + (k)],             \
                        W_hh[((rbase) + 3) * 20 + (cbase) + (k)] };           \
      (wk).v4  =        W_hh[((rbase) + 4) * 20 + (cbase) + (k)]; }
    LOADC(we0, 0, a * 5, bq * 5) LOADC(we1, 1, a * 5, bq * 5)
    LOADC(we2, 2, a * 5, bq * 5) LOADC(we3, 3, a * 5, bq * 5)
    LOADC(we4, 4, a * 5, bq * 5)
    LOADC(wo0, 0, bq * 5, a * 5) LOADC(wo1, 1, bq * 5, a * 5)
    LOADC(wo2, 2, bq * 5, a * 5) LOADC(wo3, 3, bq * 5, a * 5)
    LOADC(wo4, 4, bq * 5, a * 5)
#undef LOADC

    const bool eact = (bq == 0);  // even steps: reduction over bq
    const bool oact = (a == 0);   // odd steps:  reduction over a
    Col wie, bie, wio, bio;
#define LOADIB(wv, bv, base, act)                                             \
    { const float* pw = W_ih + (base);                                        \
      const float* p1 = b_ih + (base);                                        \
      const float* p2 = b_hh + (base);                                        \
      (wv).p01 = (v2f){ (act) ? pw[0] : 0.f, (act) ? pw[1] : 0.f };           \
      (wv).p23 = (v2f){ (act) ? pw[2] : 0.f, (act) ? pw[3] : 0.f };           \
      (wv).v4  =        (act) ? pw[4] : 0.f;                                  \
      (bv).p01 = (v2f){ (act) ? (p1[0] + p2[0]) : 0.f,                        \
                        (act) ? (p1[1] + p2[1]) : 0.f };                      \
      (bv).p23 = (v2f){ (act) ? (p1[2] + p2[2]) : 0.f,                        \
                        (act) ? (p1[3] + p2[3]) : 0.f };                      \
      (bv).v4  =        (act) ? (p1[4] + p2[4]) : 0.f; }
    LOADIB(wie, bie, a * 5,  eact)
    LOADIB(wio, bio, bq * 5, oact)
#undef LOADIB

    pinc(we0); pinc(we1); pinc(we2); pinc(we3); pinc(we4);
    pinc(wo0); pinc(wo1); pinc(wo2); pinc(wo3); pinc(wo4);
    pinc(wie); pinc(bie); pinc(wio); pinc(bio);

    v2f h01 = {0.f, 0.f}, h23 = {0.f, 0.f};
    float h4 = 0.f;

    const float* __restrict__ xb = x + (size_t)b * TT;

    // --- 40-step register blocks (10 float4 each), double-buffered (R13/R14)
#define LOAD10(P, off)                                  \
    P##0 = *(const float4*)(xb + (off));                \
    P##1 = *(const float4*)(xb + (off) + 4);            \
    P##2 = *(const float4*)(xb + (off) + 8);            \
    P##3 = *(const float4*)(xb + (off) + 12);           \
    P##4 = *(const float4*)(xb + (off) + 16);           \
    P##5 = *(const float4*)(xb + (off) + 20);           \
    P##6 = *(const float4*)(xb + (off) + 24);           \
    P##7 = *(const float4*)(xb + (off) + 28);           \
    P##8 = *(const float4*)(xb + (off) + 32);           \
    P##9 = *(const float4*)(xb + (off) + 36);

#define STEP_E(xp, H) step<H, QP_XOR1, QP_XOR2>(xp, h01, h23, h4, we0, we1, we2, we3, we4, wie, bie);
#define STEP_O(xp, H) step<H, ROR4,    ROR8   >(xp, h01, h23, h4, wo0, wo1, wo2, wo3, wo4, wio, bio);
#define RUN4(Q) {                                       \
        const v2f qlo = {Q.x, Q.y};                     \
        const v2f qhi = {Q.z, Q.w};                     \
        STEP_E(qlo, 0) STEP_O(qlo, 1)                   \
        STEP_E(qhi, 0) STEP_O(qhi, 1) }
#define RUN40(P) RUN4(P##0) RUN4(P##1) RUN4(P##2) RUN4(P##3) RUN4(P##4) \
                 RUN4(P##5) RUN4(P##6) RUN4(P##7) RUN4(P##8) RUN4(P##9)

    float4 A0, A1, A2, A3, A4, A5, A6, A7, A8, A9;
    float4 B0, B1, B2, B3, B4, B5, B6, B7, B8, B9;
    LOAD10(A, 0)    // steps 0..39
    LOAD10(B, 40)   // steps 40..79

    // 12 iterations x 80 steps = 960, then a 40-step tail from A.
    for (int it = 0; it < 12; ++it) {
        const int base = it * 80;
        const int nb = (it < 11) ? base + 120 : 960;  // clamped; stale unused

        RUN40(A)                    // steps base .. base+39
        LOAD10(A, base + 80)        // it=11 loads steps 960..999 (the tail)
        RUN40(B)                    // steps base+40 .. base+79
        LOAD10(B, nb)
    }
    RUN40(A)                        // steps 960..999

#undef RUN40
#undef RUN4
#undef STEP_E
#undef STEP_O
#undef LOAD10

    keepc(we0); keepc(we1); keepc(we2); keepc(we3); keepc(we4);
    keepc(wo0); keepc(wo1); keepc(wo2); keepc(wo3); keepc(wo4);
    keepc(wie); keepc(bie); keepc(wio); keepc(bio);

    // After step 999 (odd role), lane (a,bq) holds h[bq-slice] replicated
    // over a. Mask fc weights to a==0 lanes, dot, reduce across the group.
    float dot;
    {
        const float* pf = fc_w + bq * 5;
        float f0 = oact ? pf[0] : 0.f, f1 = oact ? pf[1] : 0.f;
        float f2 = oact ? pf[2] : 0.f, f3 = oact ? pf[3] : 0.f;
        float f4 = oact ? pf[4] : 0.f;
        dot = h01.x * f0;
        dot = __builtin_fmaf(h01.y, f1, dot);
        dot = __builtin_fmaf(h23.x, f2, dot);
        dot = __builtin_fmaf(h23.y, f3, dot);
        dot = __builtin_fmaf(h4,    f4, dot);
    }
    dot += __shfl_xor(dot, 1, 16);
    dot += __shfl_xor(dot, 2, 16);
    dot += __shfl_xor(dot, 4, 16);
    dot += __shfl_xor(dot, 8, 16);

    if (gl == 0)
        out[b] = dot + fc_b[0];
}

extern "C" void kernel_launch(void* const* d_in, const int* in_sizes, int n_in,
                              void* d_out, int out_size, void* d_ws, size_t ws_size,
                              hipStream_t stream) {
    const float* x    = (const float*)d_in[0];
    const float* W_ih = (const float*)d_in[1];
    const float* W_hh = (const float*)d_in[2];
    const float* b_ih = (const float*)d_in[3];
    const float* b_hh = (const float*)d_in[4];
    const float* fc_w = (const float*)d_in[5];
    const float* fc_b = (const float*)d_in[6];
    float* out = (float*)d_out;

    // 4096 batches * 16 lanes = 65536 threads; 64-thread blocks -> 1024
    // single-wave blocks, one per SIMD.
    const int block = 64;
    const int grid  = (4096 * 16) / block;  // 1024 blocks
    rnn_os_kernel<<<grid, block, 0, stream>>>(x, W_ih, W_hh, b_ih, b_hh,
                                              fc_w, fc_b, out);
}